// Round 8
// baseline (187.328 us; speedup 1.0000x reference)
//
#include <hip/hip_runtime.h>
#include <math.h>

// Problem constants (from reference setup_inputs)
constexpr int B = 2, S = 5, C = 256, H = 200, W = 200;
constexpr int KW = 7;              // window
constexpr int HB = 29, WB = 29;    // ceil(203/7)
constexpr int HID = 16;
constexpr int NW = HB * WB;        // 841

// ---------------------------------------------------------------------------
// Kernel 1: per-window channel sums, one 512-thread block per (b,s,c) plane.
// Phase A: thread owns (hb, x4): 7 vertically-adjacent float4 loads summed
// into LDS colg[29][200]. ONE barrier. Phase B: horizontal 7-window sums ->
// gsum (contiguous). gsum layout: [B*S*C][841]
// (R6: occupancy-insensitive -> BW-plateaued; unchanged.)
// ---------------------------------------------------------------------------
__global__ __launch_bounds__(512) void k_winsum(const float* __restrict__ feats,
                                                float* __restrict__ gsum) {
    const int blk = (int)blockIdx.x;            // (b*S+s)*C + c
    const float* src = feats + (size_t)blk * (H * W);

    __shared__ float colg[HB * W];              // 23.2 KB

    const int tid = (int)threadIdx.x;

    // Phase A: 29*50 = 1450 items
    for (int q = tid; q < HB * (W / 4); q += 512) {
        int hb = q / (W / 4);
        int x4 = q - hb * (W / 4);
        int y0 = hb * KW;
        float4 a = make_float4(0.f, 0.f, 0.f, 0.f);
#pragma unroll
        for (int i = 0; i < KW; ++i) {
            int y = y0 + i;
            if (y < H) {
                float4 v = ((const float4*)(src + (size_t)y * W))[x4];
                a.x += v.x; a.y += v.y; a.z += v.z; a.w += v.w;
            }
        }
        ((float4*)(colg + hb * W))[x4] = a;
    }
    __syncthreads();

    // Phase B: 841 horizontal window sums, contiguous store
    float* dst = gsum + (size_t)blk * NW;
    for (int p = tid; p < NW; p += 512) {
        int hb = p / WB;
        int wb = p - hb * WB;
        int x0 = wb * KW;
        float s = 0.f;
#pragma unroll
        for (int j = 0; j < KW; ++j) {
            int x = x0 + j;
            if (x < W) s += colg[hb * W + x];
        }
        dst[p] = s;
    }
}

// ---------------------------------------------------------------------------
// Kernel 2: MLP + softmax over wb. One 256-thread block per (b,s,hb).
// Thread (cg, wb), cg=0..7: partial acc[16] over 32 channels; LDS reduce
// over cg; lanes 0..28 compute logits + softmax over wb.
// ---------------------------------------------------------------------------
__global__ __launch_bounds__(256) void k_weights(const float* __restrict__ gsum,
                                                 const float* __restrict__ w1,
                                                 const float* __restrict__ b1,
                                                 const float* __restrict__ w2,
                                                 const float* __restrict__ b2,
                                                 float* __restrict__ weights) {
    int blk = blockIdx.x;
    int hb = blk % HB; blk /= HB;
    int s  = blk % S;
    int b  = blk / S;
    const int bs = b * S + s;

    __shared__ float w1s[HID * C];        // 16 KB
    __shared__ float part[8 * HID * WB];  // 14.5 KB
    __shared__ float lg[WB];

    const int tid = (int)threadIdx.x;
    for (int i = tid; i < HID * C; i += 256) w1s[i] = w1[i];
    __syncthreads();

    if (tid < 8 * WB) {                   // 232 active
        const int cg = tid / WB;          // 0..7
        const int wb = tid - cg * WB;     // 0..28
        float acc[HID];
#pragma unroll
        for (int d = 0; d < HID; ++d) acc[d] = 0.f;
        const float* g = gsum + (size_t)bs * C * NW + hb * WB + wb;
        const int c0 = cg * (C / 8);
#pragma unroll 4
        for (int c = c0; c < c0 + C / 8; ++c) {
            float gc = g[(size_t)c * NW];
#pragma unroll
            for (int d = 0; d < HID; ++d) acc[d] += gc * w1s[d * C + c];
        }
#pragma unroll
        for (int d = 0; d < HID; ++d) part[(cg * HID + d) * WB + wb] = acc[d];
    }
    __syncthreads();

    if (tid < WB) {
        float logit = b2[0];
#pragma unroll
        for (int d = 0; d < HID; ++d) {
            float a = 0.f;
#pragma unroll
            for (int cg = 0; cg < 8; ++cg) a += part[(cg * HID + d) * WB + tid];
            float h = a * (1.0f / 49.0f) + b1[d];
            logit += fmaxf(h, 0.0f) * w2[d];
        }
        lg[tid] = logit;
    }
    __syncthreads();
    if (tid < WB) {
        float m = -INFINITY;
        for (int t = 0; t < WB; ++t) m = fmaxf(m, lg[t]);
        float sum = 0.f;
        for (int t = 0; t < WB; ++t) sum += expf(lg[t] - m);
        weights[(size_t)bs * NW + hb * WB + tid] = expf(lg[tid] - m) / sum;
    }
}

// ---------------------------------------------------------------------------
// Kernel 3 (persistent-plane): one 512-thread block per (b,c); grid = 512 =
// exactly 2 blocks/CU (perfect balance). Loads the 16.8 KB weight set ONCE,
// then loops over the 29 bands with a double-buffered, register-staged
// pipeline: issue next band's loads early -> compute current band from LDS
// -> ds_write staged regs -> one barrier per band. Each slice is read as a
// fully contiguous 160 KB sequential stream. LDS 72.9 KB -> 2 blocks/CU.
// ---------------------------------------------------------------------------
__device__ __forceinline__ void load_band(const float* __restrict__ f0,
                                          size_t sstride, int hb, int tid,
                                          float4* regs) {
#pragma unroll
    for (int k = 0; k < 4; ++k) {
        int q = k * 512 + tid;
        regs[k] = make_float4(0.f, 0.f, 0.f, 0.f);
        if (q < S * 350) {
            int s = q / 350, r = q - s * 350;
            int i = r / 50;
            int y = hb * KW + i;
            if (y < H)
                regs[k] = ((const float4*)(f0 + (size_t)s * sstride +
                                           (size_t)y * W))[r - i * 50];
        }
    }
}

__device__ __forceinline__ void store_band(float* __restrict__ bufp, int tid,
                                           const float4* regs) {
    // bufp = &buf[bi][0][0], laid out [S][KW*W]; float4 element q maps to
    // slice q/350, floats (q%350)*4 within the band. 
#pragma unroll
    for (int k = 0; k < 4; ++k) {
        int q = k * 512 + tid;
        if (q < S * 350) {
            ((float4*)bufp)[q] = regs[k];
        }
    }
}

__global__ __launch_bounds__(512) void k_fuse(const float* __restrict__ feats,
                                              const float* __restrict__ weights,
                                              float* __restrict__ out) {
    const int c = (C - 1) - ((int)blockIdx.x % C);
    const int b = (B - 1) - ((int)blockIdx.x / C);

    __shared__ float buf[2][S][KW * W];   // 2 x 5 x 1400 floats = 56 KB
    __shared__ float wsl[S][NW];          // 16.8 KB

    const int tid = (int)threadIdx.x;
    const size_t plane = (size_t)H * W;
    const size_t sstride = (size_t)C * plane;
    const float* f0 = feats + ((size_t)b * S * C + c) * plane;
    float* o = out + ((size_t)b * C + c) * plane;

    // weights for this b: [s][hb*WB+wb], flat copy of 5*841 floats
    for (int q = tid; q < S * NW; q += 512)
        ((float*)wsl)[q] = weights[(size_t)b * S * NW + q];

    // prologue: stage band 0
    float4 r0[4];
    load_band(f0, sstride, 0, tid, r0);
    store_band(&buf[0][0][0], tid, r0);
    __syncthreads();

    for (int hb = 0; hb < HB; ++hb) {
        const int cur = hb & 1;
        float4 rn[4];
        if (hb + 1 < HB) load_band(f0, sstride, hb + 1, tid, rn);  // issue early

        // compute band hb from buf[cur]: 7 output rows y = i*29+hb
        if (tid < 350) {
            int i  = tid / 50;
            int y  = i * HB + hb;
            if (y < H) {
                int x0 = (tid - i * 50) * 4;
                float4 acc4;
                float* ap = (float*)&acc4;
#pragma unroll
                for (int u = 0; u < 4; ++u) {
                    int x  = x0 + u;
                    int j  = x / WB;
                    int wb = x - j * WB;
                    int x_in = wb * KW + j;
                    float acc = 0.f;
                    if (x_in < W) {
#pragma unroll
                        for (int s = 0; s < S; ++s)
                            acc += buf[cur][s][i * W + x_in] * wsl[s][hb * WB + wb];
                    }
                    ap[u] = acc;
                }
                ((float4*)(o + (size_t)y * W))[x0 / 4] = acc4;
            }
        }

        if (hb + 1 < HB) store_band(&buf[cur ^ 1][0][0], tid, rn);
        __syncthreads();
    }
}

// ---------------------------------------------------------------------------
extern "C" void kernel_launch(void* const* d_in, const int* in_sizes, int n_in,
                              void* d_out, int out_size, void* d_ws, size_t ws_size,
                              hipStream_t stream) {
    const float* feats = (const float*)d_in[0];
    const float* w1    = (const float*)d_in[1];
    const float* b1    = (const float*)d_in[2];
    const float* w2    = (const float*)d_in[3];
    const float* b2    = (const float*)d_in[4];
    float* out = (float*)d_out;

    // Workspace layout
    float* gsum    = (float*)d_ws;                      // B*S*C*841 floats
    float* weights = gsum + (size_t)B * S * C * NW;     // B*S*841 floats

    // Kernel 1: window sums (one 512-thread block per plane)
    hipLaunchKernelGGL(k_winsum, dim3(B * S * C), dim3(512), 0, stream, feats, gsum);
    // Kernel 2: MLP + softmax -> weights
    hipLaunchKernelGGL(k_weights, dim3(B * S * HB), dim3(256), 0, stream,
                       gsum, w1, b1, w2, b2, weights);
    // Kernel 3: persistent-plane weighted fusion (2 blocks/CU, double-buffered)
    hipLaunchKernelGGL(k_fuse, dim3(B * C), dim3(512), 0, stream,
                       feats, weights, out);
}

// Round 9
// 174.549 us; speedup vs baseline: 1.0732x; 1.0732x over previous
//
#include <hip/hip_runtime.h>
#include <math.h>

// Problem constants (from reference setup_inputs)
constexpr int B = 2, S = 5, C = 256, H = 200, W = 200;
constexpr int KW = 7;              // window
constexpr int HB = 29, WB = 29;    // ceil(203/7)
constexpr int HID = 16;
constexpr int NW = HB * WB;        // 841
constexpr int NG = 15;             // band-pair groups (last = band 28 alone)

// ---------------------------------------------------------------------------
// Kernel 1: per-window channel sums, one 512-thread block per (b,s,c) plane.
// Phase A: thread owns (hb, x4): 7 vertically-adjacent float4 loads summed
// into LDS colg[29][200]. ONE barrier. Phase B: horizontal 7-window sums ->
// gsum (contiguous). gsum layout: [B*S*C][841]
// (R6: occupancy-insensitive -> BW-plateaued; unchanged since R5.)
// ---------------------------------------------------------------------------
__global__ __launch_bounds__(512) void k_winsum(const float* __restrict__ feats,
                                                float* __restrict__ gsum) {
    const int blk = (int)blockIdx.x;            // (b*S+s)*C + c
    const float* src = feats + (size_t)blk * (H * W);

    __shared__ float colg[HB * W];              // 23.2 KB

    const int tid = (int)threadIdx.x;

    // Phase A: 29*50 = 1450 items
    for (int q = tid; q < HB * (W / 4); q += 512) {
        int hb = q / (W / 4);
        int x4 = q - hb * (W / 4);
        int y0 = hb * KW;
        float4 a = make_float4(0.f, 0.f, 0.f, 0.f);
#pragma unroll
        for (int i = 0; i < KW; ++i) {
            int y = y0 + i;
            if (y < H) {
                float4 v = ((const float4*)(src + (size_t)y * W))[x4];
                a.x += v.x; a.y += v.y; a.z += v.z; a.w += v.w;
            }
        }
        ((float4*)(colg + hb * W))[x4] = a;
    }
    __syncthreads();

    // Phase B: 841 horizontal window sums, contiguous store
    float* dst = gsum + (size_t)blk * NW;
    for (int p = tid; p < NW; p += 512) {
        int hb = p / WB;
        int wb = p - hb * WB;
        int x0 = wb * KW;
        float s = 0.f;
#pragma unroll
        for (int j = 0; j < KW; ++j) {
            int x = x0 + j;
            if (x < W) s += colg[hb * W + x];
        }
        dst[p] = s;
    }
}

// ---------------------------------------------------------------------------
// Kernel 2: MLP + softmax over wb. One 256-thread block per (b,s,hb).
// Thread (cg, wb), cg=0..7: partial acc[16] over 32 channels; LDS reduce
// over cg; lanes 0..28 compute logits + softmax over wb.
// ---------------------------------------------------------------------------
__global__ __launch_bounds__(256) void k_weights(const float* __restrict__ gsum,
                                                 const float* __restrict__ w1,
                                                 const float* __restrict__ b1,
                                                 const float* __restrict__ w2,
                                                 const float* __restrict__ b2,
                                                 float* __restrict__ weights) {
    int blk = blockIdx.x;
    int hb = blk % HB; blk /= HB;
    int s  = blk % S;
    int b  = blk / S;
    const int bs = b * S + s;

    __shared__ float w1s[HID * C];        // 16 KB
    __shared__ float part[8 * HID * WB];  // 14.5 KB
    __shared__ float lg[WB];

    const int tid = (int)threadIdx.x;
    for (int i = tid; i < HID * C; i += 256) w1s[i] = w1[i];
    __syncthreads();

    if (tid < 8 * WB) {                   // 232 active
        const int cg = tid / WB;          // 0..7
        const int wb = tid - cg * WB;     // 0..28
        float acc[HID];
#pragma unroll
        for (int d = 0; d < HID; ++d) acc[d] = 0.f;
        const float* g = gsum + (size_t)bs * C * NW + hb * WB + wb;
        const int c0 = cg * (C / 8);
#pragma unroll 4
        for (int c = c0; c < c0 + C / 8; ++c) {
            float gc = g[(size_t)c * NW];
#pragma unroll
            for (int d = 0; d < HID; ++d) acc[d] += gc * w1s[d * C + c];
        }
#pragma unroll
        for (int d = 0; d < HID; ++d) part[(cg * HID + d) * WB + wb] = acc[d];
    }
    __syncthreads();

    if (tid < WB) {
        float logit = b2[0];
#pragma unroll
        for (int d = 0; d < HID; ++d) {
            float a = 0.f;
#pragma unroll
            for (int cg = 0; cg < 8; ++cg) a += part[(cg * HID + d) * WB + tid];
            float h = a * (1.0f / 49.0f) + b1[d];
            logit += fmaxf(h, 0.0f) * w2[d];
        }
        lg[tid] = logit;
    }
    __syncthreads();
    if (tid < WB) {
        float m = -INFINITY;
        for (int t = 0; t < WB; ++t) m = fmaxf(m, lg[t]);
        float sum = 0.f;
        for (int t = 0; t < WB; ++t) sum += expf(lg[t] - m);
        weights[(size_t)bs * NW + hb * WB + tid] = expf(lg[tid] - m) / sum;
    }
}

// ---------------------------------------------------------------------------
// Kernel 3 (band-pair): block = (b, c, g) where g covers bands hb=2g,2g+1
// (g=14: band 28 alone). Input rows for the pair are the 14 CONTIGUOUS rows
// 14g..14g+13 -> 11.2 KB contiguous read per slice. Output rows come in
// ADJACENT pairs y = i*29+2g, i*29+2g+1 -> 1600 B write chunks.
// 1024 threads (16 waves), 56.6 KB LDS -> 2 blocks/CU = 32 waves/CU = 100%.
// Independent short-lived blocks (one barrier each) keep the R7-style
// block-level TLP staggering that R8's lockstep pipeline lost.
// Mapping reversed (b=1, high c first) as in R5-R7.
// ---------------------------------------------------------------------------
__global__ __launch_bounds__(1024) void k_fuse(const float* __restrict__ feats,
                                               const float* __restrict__ weights,
                                               float* __restrict__ out) {
    int blk = blockIdx.x;
    const int g = blk % NG; blk /= NG;
    const int c = (C - 1) - (blk % C);
    const int b = (B - 1) - (blk / C);
    const int nb = (2 * g + 1 < HB) ? 2 : 1;    // bands in this group

    __shared__ float buf[S][2 * KW * W];  // 5 x 2800 floats = 56 KB
    __shared__ float wsl[S][2][WB];       // 1.2 KB

    const int tid = (int)threadIdx.x;
    const size_t plane = (size_t)H * W;
    const size_t sstride = (size_t)C * plane;
    const float* f0 = feats + ((size_t)b * S * C + c) * plane;
    const int y_in0 = g * 2 * KW;               // first input row (14g)

    // stage: 5 slices x 700 float4; each slice one contiguous 11.2 KB range
    // (rows 14g..14g+13); zero rows past H
    for (int q = tid; q < S * 700; q += 1024) {
        int s = q / 700;
        int r = q - s * 700;               // float4 index within the 14-row band
        float4 v = make_float4(0.f, 0.f, 0.f, 0.f);
        if (y_in0 + r / 50 < H)
            v = ((const float4*)(f0 + (size_t)s * sstride + (size_t)y_in0 * W))[r];
        ((float4*)&buf[s][0])[r] = v;
    }
    // weight rows: one per (slice, band)
    if (tid < S * 2 * WB) {
        int s  = tid / (2 * WB);
        int r  = tid - s * (2 * WB);
        int k  = r / WB;
        int wb = r - k * WB;
        int hb = 2 * g + k;
        if (hb < HB)
            wsl[s][k][wb] = weights[((size_t)((b * S + s) * HB + hb)) * WB + wb];
    }
    __syncthreads();

    float* o = out + ((size_t)b * C + c) * plane;
    // outputs: nb*350 float4 (bands k=0..nb-1, rows y = i*29 + 2g+k)
    for (int p = tid; p < nb * 350; p += 1024) {
        int k  = p / 350;
        int pi = p - k * 350;
        int i  = pi / 50;
        int y  = i * HB + 2 * g + k;
        if (y < H) {
            int x0 = (pi - i * 50) * 4;
            float4 r4;
            float* rp = (float*)&r4;
#pragma unroll
            for (int u = 0; u < 4; ++u) {
                int x  = x0 + u;
                int j  = x / WB;
                int wb = x - j * WB;
                int x_in = wb * KW + j;
                float acc = 0.f;
                if (x_in < W) {
                    const int lrow = (k * KW + i) * W;
#pragma unroll
                    for (int s = 0; s < S; ++s)
                        acc += buf[s][lrow + x_in] * wsl[s][k][wb];
                }
                rp[u] = acc;
            }
            ((float4*)(o + (size_t)y * W))[x0 / 4] = r4;
        }
    }
}

// ---------------------------------------------------------------------------
extern "C" void kernel_launch(void* const* d_in, const int* in_sizes, int n_in,
                              void* d_out, int out_size, void* d_ws, size_t ws_size,
                              hipStream_t stream) {
    const float* feats = (const float*)d_in[0];
    const float* w1    = (const float*)d_in[1];
    const float* b1    = (const float*)d_in[2];
    const float* w2    = (const float*)d_in[3];
    const float* b2    = (const float*)d_in[4];
    float* out = (float*)d_out;

    // Workspace layout
    float* gsum    = (float*)d_ws;                      // B*S*C*841 floats
    float* weights = gsum + (size_t)B * S * C * NW;     // B*S*841 floats

    // Kernel 1: window sums (one 512-thread block per plane)
    hipLaunchKernelGGL(k_winsum, dim3(B * S * C), dim3(512), 0, stream, feats, gsum);
    // Kernel 2: MLP + softmax -> weights
    hipLaunchKernelGGL(k_weights, dim3(B * S * HB), dim3(256), 0, stream,
                       gsum, w1, b1, w2, b2, weights);
    // Kernel 3: band-pair weighted fusion
    hipLaunchKernelGGL(k_fuse, dim3(B * C * NG), dim3(1024), 0, stream,
                       feats, weights, out);
}